// Round 1
// baseline (2881.312 us; speedup 1.0000x reference)
//
#include <hip/hip_runtime.h>
#include <stdint.h>

#define D_IN  128
#define D_OUT 64
#define BN_EPS 1e-3f

// ---------------- GEMM: pre = X @ W  (fp32, vector ALU) ----------------
// Tile: 32 rows x 64 cols per block of 256 threads; 2x4 micro-tile/thread.
#define BM 32
#define XS_LD 132   // padded leading dim (floats): (r*132+k)/4 %32 distinct per r

__global__ __launch_bounds__(256) void gemm_kernel(
    const float* __restrict__ x, const float* __restrict__ W,
    float* __restrict__ pre, int n_nodes) {
  __shared__ float Wl[D_IN * D_OUT];      // 32 KB
  __shared__ float xs[BM * XS_LD];        // 16.9 KB
  const int t = threadIdx.x;

  // load W once (coalesced)
  for (int i = t; i < D_IN * D_OUT; i += 256) Wl[i] = W[i];

  const int tx = t & 15;        // col group: cols tx*4 .. tx*4+3
  const int ty = t >> 4;        // row group: rows ty*2 .. ty*2+1
  const int n_tiles = (n_nodes + BM - 1) / BM;

  for (int tile = blockIdx.x; tile < n_tiles; tile += gridDim.x) {
    const int row0 = tile * BM;
    __syncthreads();   // protect xs (prev iter readers) + Wl first iter
    // stage x tile: BM x 128 floats = 1024 float4, 4 per thread, coalesced
    for (int i4 = t; i4 < BM * (D_IN / 4); i4 += 256) {
      const int r = i4 >> 5;          // / (128/4)
      const int c4 = i4 & 31;
      const int row = row0 + r;
      float4 v = make_float4(0.f, 0.f, 0.f, 0.f);
      if (row < n_nodes) v = *(const float4*)&x[(size_t)row * D_IN + c4 * 4];
      *(float4*)&xs[r * XS_LD + c4 * 4] = v;
    }
    __syncthreads();

    float acc[2][4] = {};
    for (int k = 0; k < D_IN; k += 4) {
      const float4 w0 = *(const float4*)&Wl[(k + 0) * D_OUT + tx * 4];
      const float4 w1 = *(const float4*)&Wl[(k + 1) * D_OUT + tx * 4];
      const float4 w2 = *(const float4*)&Wl[(k + 2) * D_OUT + tx * 4];
      const float4 w3 = *(const float4*)&Wl[(k + 3) * D_OUT + tx * 4];
#pragma unroll
      for (int i = 0; i < 2; ++i) {
        const float4 xv = *(const float4*)&xs[(ty * 2 + i) * XS_LD + k];
        acc[i][0] += xv.x * w0.x + xv.y * w1.x + xv.z * w2.x + xv.w * w3.x;
        acc[i][1] += xv.x * w0.y + xv.y * w1.y + xv.z * w2.y + xv.w * w3.y;
        acc[i][2] += xv.x * w0.z + xv.y * w1.z + xv.z * w2.z + xv.w * w3.z;
        acc[i][3] += xv.x * w0.w + xv.y * w1.w + xv.z * w2.w + xv.w * w3.w;
      }
    }
#pragma unroll
    for (int i = 0; i < 2; ++i) {
      const int row = row0 + ty * 2 + i;
      if (row < n_nodes) {
        *(float4*)&pre[(size_t)row * D_OUT + tx * 4] =
            make_float4(acc[i][0], acc[i][1], acc[i][2], acc[i][3]);
      }
    }
  }
}

// ---------------- Scatter: out[dst] += val * pre[src]  (atomic) ----------------
// 16 threads per edge, float4 per thread (coalesced 256B gather per edge).
__global__ __launch_bounds__(256) void scatter_kernel(
    const float* __restrict__ pre, const float* __restrict__ ev,
    const int* __restrict__ esrc, const int* __restrict__ edst,
    float* __restrict__ out, int n_edges) {
  const int64_t total = (int64_t)n_edges * 16;
  const int64_t stride = (int64_t)gridDim.x * blockDim.x;
  for (int64_t i = (int64_t)blockIdx.x * blockDim.x + threadIdx.x; i < total;
       i += stride) {
    const int e = (int)(i >> 4);
    const int c4 = ((int)i & 15) * 4;
    const float v = ev[e];                 // wave-uniform within 16-lane group
    const int src = esrc[e];
    const int dst = edst[e];
    const float4 p = *(const float4*)&pre[(size_t)src * D_OUT + c4];
    float* o = &out[(size_t)dst * D_OUT + c4];
    atomicAdd(o + 0, v * p.x);
    atomicAdd(o + 1, v * p.y);
    atomicAdd(o + 2, v * p.z);
    atomicAdd(o + 3, v * p.w);
  }
}

// ---------------- BN stats: per-column sum and sumsq ----------------
// stride is a multiple of 64 -> each thread touches exactly one column.
__global__ __launch_bounds__(256) void stats_kernel(
    const float* __restrict__ out, float* __restrict__ stats, int64_t n_elems) {
  float s = 0.f, s2 = 0.f;
  const int64_t stride = (int64_t)gridDim.x * 256;
  for (int64_t i = (int64_t)blockIdx.x * 256 + threadIdx.x; i < n_elems;
       i += stride) {
    const float v = out[i];
    s += v;
    s2 += v * v;
  }
  __shared__ float ls[256], ls2[256];
  const int t = threadIdx.x;
  ls[t] = s;
  ls2[t] = s2;
  __syncthreads();
  if (t < 128) { ls[t] += ls[t + 128]; ls2[t] += ls2[t + 128]; }
  __syncthreads();
  if (t < 64) {
    const float a = ls[t] + ls[t + 64];
    const float b = ls2[t] + ls2[t + 64];
    atomicAdd(&stats[t], a);
    atomicAdd(&stats[64 + t], b);
  }
}

// ---------------- Normalize + ReLU (in place) ----------------
__global__ __launch_bounds__(256) void norm_kernel(
    float* __restrict__ out, const float* __restrict__ stats, int64_t n_elems,
    float inv_n) {
  const int c = threadIdx.x & 63;  // stride multiple of 64 -> col fixed
  const float mean = stats[c] * inv_n;
  const float var = stats[64 + c] * inv_n - mean * mean;
  const float scale = rsqrtf(var + BN_EPS);
  const int64_t stride = (int64_t)gridDim.x * 256;
  for (int64_t i = (int64_t)blockIdx.x * 256 + threadIdx.x; i < n_elems;
       i += stride) {
    const float v = (out[i] - mean) * scale;
    out[i] = v > 0.f ? v : 0.f;
  }
}

// ---------------- launch ----------------
extern "C" void kernel_launch(void* const* d_in, const int* in_sizes, int n_in,
                              void* d_out, int out_size, void* d_ws,
                              size_t ws_size, hipStream_t stream) {
  const float* x = (const float*)d_in[0];
  const float* W = (const float*)d_in[1];
  const float* ev = (const float*)d_in[2];
  const int* esrc = (const int*)d_in[3];
  const int* edst = (const int*)d_in[4];

  const int n_nodes = in_sizes[0] / D_IN;
  const int n_edges = in_sizes[2];
  const int64_t n_out = (int64_t)n_nodes * D_OUT;

  float* out = (float*)d_out;
  float* pre = (float*)d_ws;                       // n_nodes*64 floats
  float* stats = pre + (size_t)n_nodes * D_OUT;    // 128 floats

  // zero the accumulator + stats
  hipMemsetAsync(d_out, 0, (size_t)n_out * sizeof(float), stream);
  hipMemsetAsync(stats, 0, 128 * sizeof(float), stream);

  gemm_kernel<<<2048, 256, 0, stream>>>(x, W, pre, n_nodes);
  scatter_kernel<<<16384, 256, 0, stream>>>(pre, ev, esrc, edst, out, n_edges);
  stats_kernel<<<1024, 256, 0, stream>>>(out, stats, n_out);
  norm_kernel<<<2048, 256, 0, stream>>>(out, stats, n_out,
                                        1.0f / (float)n_nodes);
}

// Round 2
// 850.999 us; speedup vs baseline: 3.3858x; 3.3858x over previous
//
#include <hip/hip_runtime.h>
#include <stdint.h>

#define D_IN  128
#define D_OUT 64
#define BN_EPS 1e-3f

// ---------------- GEMM: pre = X @ W  (fp32, vector ALU) ----------------
#define BM 32
#define XS_LD 132

__global__ __launch_bounds__(256) void gemm_kernel(
    const float* __restrict__ x, const float* __restrict__ W,
    float* __restrict__ pre, int n_nodes) {
  __shared__ float Wl[D_IN * D_OUT];      // 32 KB
  __shared__ float xs[BM * XS_LD];        // 16.9 KB
  const int t = threadIdx.x;

  for (int i = t; i < D_IN * D_OUT; i += 256) Wl[i] = W[i];

  const int tx = t & 15;
  const int ty = t >> 4;
  const int n_tiles = (n_nodes + BM - 1) / BM;

  for (int tile = blockIdx.x; tile < n_tiles; tile += gridDim.x) {
    const int row0 = tile * BM;
    __syncthreads();
    for (int i4 = t; i4 < BM * (D_IN / 4); i4 += 256) {
      const int r = i4 >> 5;
      const int c4 = i4 & 31;
      const int row = row0 + r;
      float4 v = make_float4(0.f, 0.f, 0.f, 0.f);
      if (row < n_nodes) v = *(const float4*)&x[(size_t)row * D_IN + c4 * 4];
      *(float4*)&xs[r * XS_LD + c4 * 4] = v;
    }
    __syncthreads();

    float acc[2][4] = {};
    for (int k = 0; k < D_IN; k += 4) {
      const float4 w0 = *(const float4*)&Wl[(k + 0) * D_OUT + tx * 4];
      const float4 w1 = *(const float4*)&Wl[(k + 1) * D_OUT + tx * 4];
      const float4 w2 = *(const float4*)&Wl[(k + 2) * D_OUT + tx * 4];
      const float4 w3 = *(const float4*)&Wl[(k + 3) * D_OUT + tx * 4];
#pragma unroll
      for (int i = 0; i < 2; ++i) {
        const float4 xv = *(const float4*)&xs[(ty * 2 + i) * XS_LD + k];
        acc[i][0] += xv.x * w0.x + xv.y * w1.x + xv.z * w2.x + xv.w * w3.x;
        acc[i][1] += xv.x * w0.y + xv.y * w1.y + xv.z * w2.y + xv.w * w3.y;
        acc[i][2] += xv.x * w0.z + xv.y * w1.z + xv.z * w2.z + xv.w * w3.z;
        acc[i][3] += xv.x * w0.w + xv.y * w1.w + xv.z * w2.w + xv.w * w3.w;
      }
    }
#pragma unroll
    for (int i = 0; i < 2; ++i) {
      const int row = row0 + ty * 2 + i;
      if (row < n_nodes) {
        *(float4*)&pre[(size_t)row * D_OUT + tx * 4] =
            make_float4(acc[i][0], acc[i][1], acc[i][2], acc[i][3]);
      }
    }
  }
}

// ---------------- CSR build: histogram -> scan -> fill ----------------
__global__ __launch_bounds__(256) void hist_kernel(
    const int* __restrict__ edst, int* __restrict__ counts, int n_edges) {
  const int i = blockIdx.x * 256 + threadIdx.x;
  if (i < n_edges) atomicAdd(&counts[edst[i]], 1);
}

// single block of 1024 threads: exclusive scan of counts -> offsets, zero counts
__global__ __launch_bounds__(1024) void scan_kernel(
    int* __restrict__ counts, int* __restrict__ offsets, int n) {
  __shared__ int ls[1024];
  const int t = threadIdx.x;
  const int chunk = (n + 1023) >> 10;
  const int beg = t * chunk;
  const int end = min(beg + chunk, n);
  int s = 0;
  for (int i = beg; i < end; ++i) s += counts[i];
  ls[t] = s;
  __syncthreads();
  for (int off = 1; off < 1024; off <<= 1) {
    const int v = (t >= off) ? ls[t - off] : 0;
    __syncthreads();
    ls[t] += v;
    __syncthreads();
  }
  int run = ls[t] - s;  // exclusive prefix of this thread's chunk
  for (int i = beg; i < end; ++i) {
    const int c = counts[i];
    offsets[i] = run;
    run += c;
    counts[i] = 0;  // reset as fill cursor
  }
}

__global__ __launch_bounds__(256) void fill_kernel(
    const float* __restrict__ ev, const int* __restrict__ esrc,
    const int* __restrict__ edst, const int* __restrict__ offsets,
    int* __restrict__ counts, int2* __restrict__ bucket, int n_edges) {
  const int i = blockIdx.x * 256 + threadIdx.x;
  if (i >= n_edges) return;
  const int dst = edst[i];
  const int pos = atomicAdd(&counts[dst], 1);
  bucket[offsets[dst] + pos] = make_int2(esrc[i], __float_as_int(ev[i]));
}

// ---------------- Gather: one 64-lane wave per dst node ----------------
__global__ __launch_bounds__(256) void gather_kernel(
    const float* __restrict__ pre, const int2* __restrict__ bucket,
    const int* __restrict__ offsets, const int* __restrict__ counts,
    float* __restrict__ out, int n_nodes) {
  const int node = blockIdx.x * 4 + (threadIdx.x >> 6);
  if (node >= n_nodes) return;
  const int lane = threadIdx.x & 63;
  const int beg = offsets[node];
  const int deg = counts[node];  // restored to degree by fill
  float acc0 = 0.f, acc1 = 0.f;
  int j = 0;
  for (; j + 1 < deg; j += 2) {
    const int2 r0 = bucket[beg + j];       // wave-broadcast load
    const int2 r1 = bucket[beg + j + 1];
    acc0 += __int_as_float(r0.y) * pre[(size_t)r0.x * D_OUT + lane];
    acc1 += __int_as_float(r1.y) * pre[(size_t)r1.x * D_OUT + lane];
  }
  if (j < deg) {
    const int2 r = bucket[beg + j];
    acc0 += __int_as_float(r.y) * pre[(size_t)r.x * D_OUT + lane];
  }
  out[(size_t)node * D_OUT + lane] = acc0 + acc1;
}

// ---------------- BN stats ----------------
__global__ __launch_bounds__(256) void stats_kernel(
    const float* __restrict__ out, float* __restrict__ stats, int64_t n_elems) {
  float s = 0.f, s2 = 0.f;
  const int64_t stride = (int64_t)gridDim.x * 256;
  for (int64_t i = (int64_t)blockIdx.x * 256 + threadIdx.x; i < n_elems;
       i += stride) {
    const float v = out[i];
    s += v;
    s2 += v * v;
  }
  __shared__ float ls[256], ls2[256];
  const int t = threadIdx.x;
  ls[t] = s;
  ls2[t] = s2;
  __syncthreads();
  if (t < 128) { ls[t] += ls[t + 128]; ls2[t] += ls2[t + 128]; }
  __syncthreads();
  if (t < 64) {
    atomicAdd(&stats[t], ls[t] + ls[t + 64]);
    atomicAdd(&stats[64 + t], ls2[t] + ls2[t + 64]);
  }
}

// ---------------- Normalize + ReLU (in place) ----------------
__global__ __launch_bounds__(256) void norm_kernel(
    float* __restrict__ out, const float* __restrict__ stats, int64_t n_elems,
    float inv_n) {
  const int c = threadIdx.x & 63;
  const float mean = stats[c] * inv_n;
  const float var = stats[64 + c] * inv_n - mean * mean;
  const float scale = rsqrtf(var + BN_EPS);
  const int64_t stride = (int64_t)gridDim.x * 256;
  for (int64_t i = (int64_t)blockIdx.x * 256 + threadIdx.x; i < n_elems;
       i += stride) {
    const float v = (out[i] - mean) * scale;
    out[i] = v > 0.f ? v : 0.f;
  }
}

// ---------------- launch ----------------
extern "C" void kernel_launch(void* const* d_in, const int* in_sizes, int n_in,
                              void* d_out, int out_size, void* d_ws,
                              size_t ws_size, hipStream_t stream) {
  const float* x = (const float*)d_in[0];
  const float* W = (const float*)d_in[1];
  const float* ev = (const float*)d_in[2];
  const int* esrc = (const int*)d_in[3];
  const int* edst = (const int*)d_in[4];

  const int n_nodes = in_sizes[0] / D_IN;
  const int n_edges = in_sizes[2];
  const int64_t n_out = (int64_t)n_nodes * D_OUT;

  float* out = (float*)d_out;

  // workspace layout (8B-aligned slices)
  char* w = (char*)d_ws;
  float* pre = (float*)w;                 w += (size_t)n_nodes * D_OUT * 4;
  int* counts = (int*)w;                  w += (size_t)n_nodes * 4;
  int* offsets = (int*)w;                 w += (size_t)n_nodes * 4;
  float* stats = (float*)w;               w += 128 * 4;
  w = (char*)(((uintptr_t)w + 7) & ~(uintptr_t)7);
  int2* bucket = (int2*)w;                // n_edges * 8 bytes

  hipMemsetAsync(counts, 0, (size_t)n_nodes * 4, stream);
  hipMemsetAsync(stats, 0, 128 * 4, stream);

  const int eblocks = (n_edges + 255) / 256;
  gemm_kernel<<<2048, 256, 0, stream>>>(x, W, pre, n_nodes);
  hist_kernel<<<eblocks, 256, 0, stream>>>(edst, counts, n_edges);
  scan_kernel<<<1, 1024, 0, stream>>>(counts, offsets, n_nodes);
  fill_kernel<<<eblocks, 256, 0, stream>>>(ev, esrc, edst, offsets, counts,
                                           bucket, n_edges);
  gather_kernel<<<(n_nodes + 3) / 4, 256, 0, stream>>>(pre, bucket, offsets,
                                                       counts, out, n_nodes);
  stats_kernel<<<1024, 256, 0, stream>>>(out, stats, n_out);
  norm_kernel<<<2048, 256, 0, stream>>>(out, stats, n_out,
                                        1.0f / (float)n_nodes);
}

// Round 3
// 638.225 us; speedup vs baseline: 4.5146x; 1.3334x over previous
//
#include <hip/hip_runtime.h>
#include <stdint.h>

#define D_IN  128
#define D_OUT 64
#define BN_EPS 1e-3f
#define SCAN_BLOCKS 256

// ---------------- GEMM: pre = X @ W  (fp32, vector ALU) ----------------
#define BM 32
#define XS_LD 132

__global__ __launch_bounds__(256) void gemm_kernel(
    const float* __restrict__ x, const float* __restrict__ W,
    float* __restrict__ pre, int n_nodes) {
  __shared__ float Wl[D_IN * D_OUT];      // 32 KB
  __shared__ float xs[BM * XS_LD];        // 16.9 KB
  const int t = threadIdx.x;

  for (int i = t; i < D_IN * D_OUT; i += 256) Wl[i] = W[i];

  const int tx = t & 15;
  const int ty = t >> 4;
  const int n_tiles = (n_nodes + BM - 1) / BM;

  for (int tile = blockIdx.x; tile < n_tiles; tile += gridDim.x) {
    const int row0 = tile * BM;
    __syncthreads();
    for (int i4 = t; i4 < BM * (D_IN / 4); i4 += 256) {
      const int r = i4 >> 5;
      const int c4 = i4 & 31;
      const int row = row0 + r;
      float4 v = make_float4(0.f, 0.f, 0.f, 0.f);
      if (row < n_nodes) v = *(const float4*)&x[(size_t)row * D_IN + c4 * 4];
      *(float4*)&xs[r * XS_LD + c4 * 4] = v;
    }
    __syncthreads();

    float acc[2][4] = {};
    for (int k = 0; k < D_IN; k += 4) {
      const float4 w0 = *(const float4*)&Wl[(k + 0) * D_OUT + tx * 4];
      const float4 w1 = *(const float4*)&Wl[(k + 1) * D_OUT + tx * 4];
      const float4 w2 = *(const float4*)&Wl[(k + 2) * D_OUT + tx * 4];
      const float4 w3 = *(const float4*)&Wl[(k + 3) * D_OUT + tx * 4];
#pragma unroll
      for (int i = 0; i < 2; ++i) {
        const float4 xv = *(const float4*)&xs[(ty * 2 + i) * XS_LD + k];
        acc[i][0] += xv.x * w0.x + xv.y * w1.x + xv.z * w2.x + xv.w * w3.x;
        acc[i][1] += xv.x * w0.y + xv.y * w1.y + xv.z * w2.y + xv.w * w3.y;
        acc[i][2] += xv.x * w0.z + xv.y * w1.z + xv.z * w2.z + xv.w * w3.z;
        acc[i][3] += xv.x * w0.w + xv.y * w1.w + xv.z * w2.w + xv.w * w3.w;
      }
    }
#pragma unroll
    for (int i = 0; i < 2; ++i) {
      const int row = row0 + ty * 2 + i;
      if (row < n_nodes) {
        *(float4*)&pre[(size_t)row * D_OUT + tx * 4] =
            make_float4(acc[i][0], acc[i][1], acc[i][2], acc[i][3]);
      }
    }
  }
}

// ---------------- CSR build: histogram -> 3-pass scan -> fill ----------------
__global__ __launch_bounds__(256) void hist_kernel(
    const int* __restrict__ edst, int* __restrict__ counts, int n_edges) {
  const int i = blockIdx.x * 256 + threadIdx.x;
  if (i < n_edges) atomicAdd(&counts[edst[i]], 1);
}

// pass A: per-block segment sums
__global__ __launch_bounds__(256) void scan_a_kernel(
    const int* __restrict__ counts, int* __restrict__ partial, int n) {
  const int b = blockIdx.x, t = threadIdx.x;
  const int seg = (n + SCAN_BLOCKS - 1) / SCAN_BLOCKS;
  const int beg = b * seg, end = min(beg + seg, n);
  const int cpt = (seg + 255) >> 8;
  const int tb = beg + t * cpt, te = min(tb + cpt, end);
  int s = 0;
  for (int i = tb; i < te; ++i) s += counts[i];
  __shared__ int ls[256];
  ls[t] = s;
  __syncthreads();
  for (int off = 128; off > 0; off >>= 1) {
    if (t < off) ls[t] += ls[t + off];
    __syncthreads();
  }
  if (t == 0) partial[b] = ls[0];
}

// pass B: exclusive scan of the 256 partials (one block)
__global__ __launch_bounds__(256) void scan_b_kernel(int* __restrict__ partial) {
  const int t = threadIdx.x;
  __shared__ int ls[256];
  const int v = partial[t];
  ls[t] = v;
  __syncthreads();
  for (int off = 1; off < 256; off <<= 1) {
    const int u = (t >= off) ? ls[t - off] : 0;
    __syncthreads();
    ls[t] += u;
    __syncthreads();
  }
  partial[t] = ls[t] - v;  // exclusive
}

// pass C: in-segment exclusive scan + base; write offsets, zero counts
__global__ __launch_bounds__(256) void scan_c_kernel(
    int* __restrict__ counts, int* __restrict__ offsets,
    const int* __restrict__ partial, int n) {
  const int b = blockIdx.x, t = threadIdx.x;
  const int seg = (n + SCAN_BLOCKS - 1) / SCAN_BLOCKS;
  const int beg = b * seg, end = min(beg + seg, n);
  const int cpt = (seg + 255) >> 8;
  const int tb = beg + t * cpt, te = min(tb + cpt, end);
  int s = 0;
  for (int i = tb; i < te; ++i) s += counts[i];
  __shared__ int ls[256];
  ls[t] = s;
  __syncthreads();
  for (int off = 1; off < 256; off <<= 1) {
    const int u = (t >= off) ? ls[t - off] : 0;
    __syncthreads();
    ls[t] += u;
    __syncthreads();
  }
  int run = partial[b] + ls[t] - s;  // exclusive prefix for this thread
  for (int i = tb; i < te; ++i) {
    const int c = counts[i];
    offsets[i] = run;
    run += c;
    counts[i] = 0;  // reset as fill cursor
  }
}

__global__ __launch_bounds__(256) void fill_kernel(
    const float* __restrict__ ev, const int* __restrict__ esrc,
    const int* __restrict__ edst, const int* __restrict__ offsets,
    int* __restrict__ counts, int2* __restrict__ bucket, int n_edges) {
  const int i = blockIdx.x * 256 + threadIdx.x;
  if (i >= n_edges) return;
  const int dst = edst[i];
  const int pos = atomicAdd(&counts[dst], 1);
  bucket[offsets[dst] + pos] = make_int2(esrc[i], __float_as_int(ev[i]));
}

// ---------------- Gather: one 64-lane wave per dst node ----------------
__global__ __launch_bounds__(256) void gather_kernel(
    const float* __restrict__ pre, const int2* __restrict__ bucket,
    const int* __restrict__ offsets, const int* __restrict__ counts,
    float* __restrict__ out, int n_nodes) {
  const int node = blockIdx.x * 4 + (threadIdx.x >> 6);
  if (node >= n_nodes) return;
  const int lane = threadIdx.x & 63;
  const int beg = offsets[node];
  const int deg = counts[node];  // restored to degree by fill
  float acc0 = 0.f, acc1 = 0.f;
  int j = 0;
  for (; j + 1 < deg; j += 2) {
    const int2 r0 = bucket[beg + j];       // wave-broadcast load
    const int2 r1 = bucket[beg + j + 1];
    acc0 += __int_as_float(r0.y) * pre[(size_t)r0.x * D_OUT + lane];
    acc1 += __int_as_float(r1.y) * pre[(size_t)r1.x * D_OUT + lane];
  }
  if (j < deg) {
    const int2 r = bucket[beg + j];
    acc0 += __int_as_float(r.y) * pre[(size_t)r.x * D_OUT + lane];
  }
  out[(size_t)node * D_OUT + lane] = acc0 + acc1;
}

// ---------------- BN stats ----------------
__global__ __launch_bounds__(256) void stats_kernel(
    const float* __restrict__ out, float* __restrict__ stats, int64_t n_elems) {
  float s = 0.f, s2 = 0.f;
  const int64_t stride = (int64_t)gridDim.x * 256;
  for (int64_t i = (int64_t)blockIdx.x * 256 + threadIdx.x; i < n_elems;
       i += stride) {
    const float v = out[i];
    s += v;
    s2 += v * v;
  }
  __shared__ float ls[256], ls2[256];
  const int t = threadIdx.x;
  ls[t] = s;
  ls2[t] = s2;
  __syncthreads();
  if (t < 128) { ls[t] += ls[t + 128]; ls2[t] += ls2[t + 128]; }
  __syncthreads();
  if (t < 64) {
    atomicAdd(&stats[t], ls[t] + ls[t + 64]);
    atomicAdd(&stats[64 + t], ls2[t] + ls2[t + 64]);
  }
}

// ---------------- Normalize + ReLU (in place) ----------------
__global__ __launch_bounds__(256) void norm_kernel(
    float* __restrict__ out, const float* __restrict__ stats, int64_t n_elems,
    float inv_n) {
  const int c = threadIdx.x & 63;
  const float mean = stats[c] * inv_n;
  const float var = stats[64 + c] * inv_n - mean * mean;
  const float scale = rsqrtf(var + BN_EPS);
  const int64_t stride = (int64_t)gridDim.x * 256;
  for (int64_t i = (int64_t)blockIdx.x * 256 + threadIdx.x; i < n_elems;
       i += stride) {
    const float v = (out[i] - mean) * scale;
    out[i] = v > 0.f ? v : 0.f;
  }
}

// ---------------- launch ----------------
extern "C" void kernel_launch(void* const* d_in, const int* in_sizes, int n_in,
                              void* d_out, int out_size, void* d_ws,
                              size_t ws_size, hipStream_t stream) {
  const float* x = (const float*)d_in[0];
  const float* W = (const float*)d_in[1];
  const float* ev = (const float*)d_in[2];
  const int* esrc = (const int*)d_in[3];
  const int* edst = (const int*)d_in[4];

  const int n_nodes = in_sizes[0] / D_IN;
  const int n_edges = in_sizes[2];
  const int64_t n_out = (int64_t)n_nodes * D_OUT;

  float* out = (float*)d_out;

  // workspace layout (8B-aligned slices)
  char* w = (char*)d_ws;
  float* pre = (float*)w;                 w += (size_t)n_nodes * D_OUT * 4;
  int* counts = (int*)w;                  w += (size_t)n_nodes * 4;
  int* offsets = (int*)w;                 w += (size_t)n_nodes * 4;
  int* partial = (int*)w;                 w += SCAN_BLOCKS * 4;
  float* stats = (float*)w;               w += 128 * 4;
  w = (char*)(((uintptr_t)w + 7) & ~(uintptr_t)7);
  int2* bucket = (int2*)w;                // n_edges * 8 bytes

  hipMemsetAsync(counts, 0, (size_t)n_nodes * 4, stream);
  hipMemsetAsync(stats, 0, 128 * 4, stream);

  const int eblocks = (n_edges + 255) / 256;
  gemm_kernel<<<2048, 256, 0, stream>>>(x, W, pre, n_nodes);
  hist_kernel<<<eblocks, 256, 0, stream>>>(edst, counts, n_edges);
  scan_a_kernel<<<SCAN_BLOCKS, 256, 0, stream>>>(counts, partial, n_nodes);
  scan_b_kernel<<<1, 256, 0, stream>>>(partial);
  scan_c_kernel<<<SCAN_BLOCKS, 256, 0, stream>>>(counts, offsets, partial,
                                                 n_nodes);
  fill_kernel<<<eblocks, 256, 0, stream>>>(ev, esrc, edst, offsets, counts,
                                           bucket, n_edges);
  gather_kernel<<<(n_nodes + 3) / 4, 256, 0, stream>>>(pre, bucket, offsets,
                                                       counts, out, n_nodes);
  stats_kernel<<<1024, 256, 0, stream>>>(out, stats, n_out);
  norm_kernel<<<2048, 256, 0, stream>>>(out, stats, n_out,
                                        1.0f / (float)n_nodes);
}